// Round 6
// baseline (89.403 us; speedup 1.0000x reference)
//
#include <hip/hip_runtime.h>

#define NB 8
#define NN 2048
#define ND 128

typedef float f32x4 __attribute__((ext_vector_type(4)));
typedef __bf16 bf16x8 __attribute__((ext_vector_type(8)));
typedef unsigned short u16x4 __attribute__((ext_vector_type(4)));

__device__ __forceinline__ unsigned short f2bf(float f) {
  unsigned u = __builtin_bit_cast(unsigned, f);
  u = (u + 0x7FFFu + ((u >> 16) & 1u)) >> 16;
  return (unsigned short)u;
}

// async 16B global->LDS (DMA path, bypasses VGPRs and the per-lane miss queue)
__device__ __forceinline__ void stage16(const void* g, void* l) {
  __builtin_amdgcn_global_load_lds(
      (const __attribute__((address_space(1))) unsigned int*)g,
      (__attribute__((address_space(3))) unsigned int*)l, 16, 0, 0);
}

// K1: h = x @ W^T + b (fp32). hn = L2norm(h) bf16 [B*N, D]; hT = h bf16 [B, D, N].
__global__ __launch_bounds__(512, 2) void k_linear(
    const float* __restrict__ x, const float* __restrict__ W,
    const float* __restrict__ bias,
    unsigned short* __restrict__ hn, unsigned short* __restrict__ hT) {
  __shared__ __align__(16) float xs[128][68];
  __shared__ __align__(16) float wt[128][128];
  const int tid = threadIdx.x;
  const int rbase = blockIdx.x * 64;
  const int b = rbase >> 11;
  const int nb = rbase & (NN - 1);

#pragma unroll
  for (int j = 0; j < 4; ++j) {
    int f = tid + j * 512;
    int row = f >> 5;
    int kc = (f & 31) << 2;
    f32x4 v = *reinterpret_cast<const f32x4*>(&x[(size_t)(rbase + row) * ND + kc]);
#pragma unroll
    for (int i2 = 0; i2 < 4; ++i2) {
      int k = kc + i2;
      xs[k][row ^ (k & 28)] = v[i2];
    }
  }
#pragma unroll
  for (int j = 0; j < 8; ++j) {
    int f = tid + j * 512;
    int o = f >> 5;
    int i0 = (f & 31) << 2;
    f32x4 v = *reinterpret_cast<const f32x4*>(&W[(size_t)o * ND + i0]);
#pragma unroll
    for (int i2 = 0; i2 < 4; ++i2) {
      int k = i0 + i2;
      wt[k][o ^ (k & 28)] = v[i2];
    }
  }
  __syncthreads();

  const int tc = tid & 31;
  const int tr = tid >> 5;

  float acc[4][4];
#pragma unroll
  for (int r = 0; r < 4; ++r)
#pragma unroll
    for (int c = 0; c < 4; ++c) acc[r][c] = 0.f;

#pragma unroll 4
  for (int k = 0; k < 128; ++k) {
    const int sw = k & 28;
    f32x4 xv = *reinterpret_cast<const f32x4*>(&xs[k][(tr * 4) ^ sw]);
    f32x4 wv = *reinterpret_cast<const f32x4*>(&wt[k][(tc * 4) ^ sw]);
#pragma unroll
    for (int r = 0; r < 4; ++r)
#pragma unroll
      for (int c = 0; c < 4; ++c) acc[r][c] += xv[r] * wv[c];
  }

  f32x4 bv = *reinterpret_cast<const f32x4*>(&bias[tc * 4]);
#pragma unroll
  for (int r = 0; r < 4; ++r)
#pragma unroll
    for (int c = 0; c < 4; ++c) acc[r][c] += bv[c];

  float inv[4];
#pragma unroll
  for (int r = 0; r < 4; ++r) {
    float s = acc[r][0] * acc[r][0] + acc[r][1] * acc[r][1] +
              acc[r][2] * acc[r][2] + acc[r][3] * acc[r][3];
#pragma unroll
    for (int d = 1; d < 32; d <<= 1) s += __shfl_xor(s, d, 32);
    inv[r] = 1.f / fmaxf(sqrtf(s), 1e-12f);
  }

#pragma unroll
  for (int r = 0; r < 4; ++r) {
    u16x4 hv;
#pragma unroll
    for (int c = 0; c < 4; ++c) hv[c] = f2bf(acc[r][c] * inv[r]);
    *reinterpret_cast<u16x4*>(&hn[(size_t)(rbase + tr * 4 + r) * ND + tc * 4]) = hv;
  }
#pragma unroll
  for (int c = 0; c < 4; ++c) {
    u16x4 tv;
#pragma unroll
    for (int r = 0; r < 4; ++r) tv[r] = f2bf(acc[r][c]);
    *reinterpret_cast<u16x4*>(
        &hT[((size_t)b * ND + tc * 4 + c) * NN + nb + tr * 4]) = tv;
  }
}

// K2: out += (edge * (hn hn^T)) @ h  for this block's 512-key range (fp32 atomics).
// 512 blocks = (b = bid&7 [XCD], qt = 128 q-rows, kh = key quarter), 8 waves.
// K (64x128 bf16) and V (128x64 bf16) tiles staged per block via global_load_lds
// with involutive XOR swizzle: LDS linear dest + inverse-swizzled global source,
// swizzled ds_read (rule #21). 51 KB LDS -> 2 blocks/CU resident (grid-limited).
__global__ __launch_bounds__(512, 4) void k_fused(
    const float* __restrict__ edge,
    const unsigned short* __restrict__ hn,
    const unsigned short* __restrict__ hT,
    float* __restrict__ out) {
  __shared__ __align__(16) unsigned short Klds[64 * 128];  // [key][d], 16B-slot swz
  __shared__ __align__(16) unsigned short Vlds[128 * 64];  // [feat][key], swz
  __shared__ __align__(16) unsigned short p_lds[8][16][68];

  const int tid = threadIdx.x;
  const int w = tid >> 6;
  const int l = tid & 63;
  const int m = l & 15;
  const int g = l >> 4;

  const int bid = blockIdx.x;
  const int b = bid & 7;          // XCD-batch affinity
  const int qt = (bid >> 3) & 15;
  const int kh = bid >> 7;        // 0..3 key quarter

  const int q0 = qt * 128 + w * 16;
  const unsigned short* hnb = hn + (size_t)b * NN * ND;
  const unsigned short* hTb = hT + (size_t)b * ND * NN;

  // Q fragments (one-time, 16 q-rows of hn)
  bf16x8 bq[4];
  {
    const unsigned short* qp = hnb + (size_t)(q0 + m) * ND + g * 8;
#pragma unroll
    for (int kst = 0; kst < 4; ++kst)
      bq[kst] = *reinterpret_cast<const bf16x8*>(qp + kst * 32);
  }

  f32x4 acc_o[8];
#pragma unroll
  for (int i = 0; i < 8; ++i) acc_o[i] = (f32x4){0.f, 0.f, 0.f, 0.f};

  const float* ep = edge + (size_t)b * NN * NN + (size_t)(q0 + m) * NN + kh * 512;

  for (int kt = 0; kt < 8; ++kt) {
    const int kb = kh * 512 + kt * 64;

    // --- stage K tile: 1024 chunks of 16B; chunk ch -> row r=ch>>4, slot c=ch&15;
    //     source slot = c ^ (r&7) so a swizzled ds_read sees the natural layout.
#pragma unroll
    for (int i = 0; i < 2; ++i) {
      int ch = tid + i * 512;
      int r = ch >> 4, c = ch & 15;
      int sc = c ^ (r & 7);
      stage16(hnb + (size_t)(kb + r) * ND + sc * 8,
              (void*)((char*)Klds + (size_t)(w * 64 + i * 512) * 16));
    }
    // --- stage V tile: row f=ch>>3 (128B rows), slot c=ch&7; src slot = c^(f&7)
#pragma unroll
    for (int i = 0; i < 2; ++i) {
      int ch = tid + i * 512;
      int f = ch >> 3, c = ch & 7;
      int sc = c ^ (f & 7);
      stage16(hTb + (size_t)f * NN + kb + sc * 8,
              (void*)((char*)Vlds + (size_t)(w * 64 + i * 512) * 16));
    }

    // edge for this tile (read-once stream, non-temporal), overlaps staging
    f32x4 eg[4];
#pragma unroll
    for (int ct = 0; ct < 4; ++ct)
      eg[ct] = __builtin_nontemporal_load(
          reinterpret_cast<const f32x4*>(ep + kt * 64 + ct * 16 + g * 4));

    __syncthreads();  // vmcnt(0) drain: staging + edge complete

    // S^T = K Q^T : A = K rows (from LDS, swizzled read), B = Q regs
    f32x4 st[4];
#pragma unroll
    for (int ct = 0; ct < 4; ++ct) {
      st[ct] = (f32x4){0.f, 0.f, 0.f, 0.f};
      const int r = ct * 16 + m;
#pragma unroll
      for (int kst = 0; kst < 4; ++kst) {
        const int slot = (kst * 4 + g) ^ (r & 7);
        bf16x8 ak = *reinterpret_cast<const bf16x8*>(&Klds[r * 128 + slot * 8]);
        st[ct] = __builtin_amdgcn_mfma_f32_16x16x32_bf16(ak, bq[kst], st[ct], 0, 0, 0);
      }
    }

    // gate, pack P[q][key] into per-wave LDS
#pragma unroll
    for (int ct = 0; ct < 4; ++ct) {
      u16x4 pv;
#pragma unroll
      for (int r = 0; r < 4; ++r) pv[r] = f2bf(eg[ct][r] * st[ct][r]);
      *reinterpret_cast<u16x4*>(&p_lds[w][m][ct * 16 + g * 4]) = pv;
    }

    // out += P @ h : A = P (LDS), B = V tile (LDS, swizzled read)
#pragma unroll
    for (int kst2 = 0; kst2 < 2; ++kst2) {
      bf16x8 ap = *reinterpret_cast<const bf16x8*>(&p_lds[w][m][kst2 * 32 + g * 8]);
#pragma unroll
      for (int ct2 = 0; ct2 < 8; ++ct2) {
        const int c = ct2 * 16 + m;
        const int slot = (kst2 * 4 + g) ^ (c & 7);
        bf16x8 bv2 = *reinterpret_cast<const bf16x8*>(&Vlds[c * 64 + slot * 8]);
        acc_o[ct2] = __builtin_amdgcn_mfma_f32_16x16x32_bf16(ap, bv2, acc_o[ct2], 0, 0, 0);
      }
    }

    __syncthreads();  // compute done before next tile's staging overwrites
  }

  // merge the 4 key-quarters across blocks
  float* ob = out + ((size_t)b * NN + q0) * ND;
#pragma unroll
  for (int ct2 = 0; ct2 < 8; ++ct2)
#pragma unroll
    for (int r = 0; r < 4; ++r)
      atomicAdd(&ob[(size_t)(g * 4 + r) * ND + ct2 * 16 + m], acc_o[ct2][r]);
}

// fast zero of d_out (replaces rocclr fillBuffer which ran at 109 GB/s)
__global__ __launch_bounds__(512) void k_zero(float* __restrict__ out, int n4) {
  int i = blockIdx.x * 512 + threadIdx.x;
  if (i < n4) reinterpret_cast<f32x4*>(out)[i] = (f32x4){0.f, 0.f, 0.f, 0.f};
}

__global__ __launch_bounds__(256) void k_relu(float* __restrict__ out, int n4) {
  int i = blockIdx.x * 256 + threadIdx.x;
  if (i < n4) {
    f32x4 v = reinterpret_cast<f32x4*>(out)[i];
#pragma unroll
    for (int j = 0; j < 4; ++j) v[j] = fmaxf(v[j], 0.f);
    reinterpret_cast<f32x4*>(out)[i] = v;
  }
}

extern "C" void kernel_launch(void* const* d_in, const int* in_sizes, int n_in,
                              void* d_out, int out_size, void* d_ws, size_t ws_size,
                              hipStream_t stream) {
  const float* x = (const float*)d_in[0];
  const float* edge = (const float*)d_in[1];
  const float* W = (const float*)d_in[2];
  const float* bias = (const float*)d_in[3];
  float* out = (float*)d_out;

  unsigned short* hn = (unsigned short*)d_ws;
  unsigned short* hT = hn + (size_t)NB * NN * ND;

  const int n4 = out_size / 4;
  k_zero<<<dim3((n4 + 511) / 512), dim3(512), 0, stream>>>(out, n4);
  k_linear<<<dim3((NB * NN) / 64), dim3(512), 0, stream>>>(x, W, bias, hn, hT);
  k_fused<<<dim3(512), dim3(512), 0, stream>>>(edge, hn, hT, out);
  k_relu<<<dim3((n4 + 255) / 256), dim3(256), 0, stream>>>(out, n4);
}

// Round 7
// 74.724 us; speedup vs baseline: 1.1964x; 1.1964x over previous
//
#include <hip/hip_runtime.h>

#define NB 8
#define NN 2048
#define ND 128

typedef float f32x4 __attribute__((ext_vector_type(4)));
typedef __bf16 bf16x8 __attribute__((ext_vector_type(8)));
typedef unsigned short u16x4 __attribute__((ext_vector_type(4)));

__device__ __forceinline__ unsigned short f2bf(float f) {
  unsigned u = __builtin_bit_cast(unsigned, f);
  u = (u + 0x7FFFu + ((u >> 16) & 1u)) >> 16;
  return (unsigned short)u;
}

// async 16B global->LDS (DMA path); LDS dest = wave-uniform base + lane*16
__device__ __forceinline__ void stage16(const void* g, void* l) {
  __builtin_amdgcn_global_load_lds(
      (const __attribute__((address_space(1))) unsigned int*)g,
      (__attribute__((address_space(3))) unsigned int*)l, 16, 0, 0);
}

// K1: h = x @ W^T + b (fp32). hn = L2norm(h) bf16 [B*N, D]; hT = h bf16 [B, D, N].
__global__ __launch_bounds__(512, 2) void k_linear(
    const float* __restrict__ x, const float* __restrict__ W,
    const float* __restrict__ bias,
    unsigned short* __restrict__ hn, unsigned short* __restrict__ hT) {
  __shared__ __align__(16) float xs[128][68];
  __shared__ __align__(16) float wt[128][128];
  const int tid = threadIdx.x;
  const int rbase = blockIdx.x * 64;
  const int b = rbase >> 11;
  const int nb = rbase & (NN - 1);

#pragma unroll
  for (int j = 0; j < 4; ++j) {
    int f = tid + j * 512;
    int row = f >> 5;
    int kc = (f & 31) << 2;
    f32x4 v = *reinterpret_cast<const f32x4*>(&x[(size_t)(rbase + row) * ND + kc]);
#pragma unroll
    for (int i2 = 0; i2 < 4; ++i2) {
      int k = kc + i2;
      xs[k][row ^ (k & 28)] = v[i2];
    }
  }
#pragma unroll
  for (int j = 0; j < 8; ++j) {
    int f = tid + j * 512;
    int o = f >> 5;
    int i0 = (f & 31) << 2;
    f32x4 v = *reinterpret_cast<const f32x4*>(&W[(size_t)o * ND + i0]);
#pragma unroll
    for (int i2 = 0; i2 < 4; ++i2) {
      int k = i0 + i2;
      wt[k][o ^ (k & 28)] = v[i2];
    }
  }
  __syncthreads();

  const int tc = tid & 31;
  const int tr = tid >> 5;

  float acc[4][4];
#pragma unroll
  for (int r = 0; r < 4; ++r)
#pragma unroll
    for (int c = 0; c < 4; ++c) acc[r][c] = 0.f;

#pragma unroll 4
  for (int k = 0; k < 128; ++k) {
    const int sw = k & 28;
    f32x4 xv = *reinterpret_cast<const f32x4*>(&xs[k][(tr * 4) ^ sw]);
    f32x4 wv = *reinterpret_cast<const f32x4*>(&wt[k][(tc * 4) ^ sw]);
#pragma unroll
    for (int r = 0; r < 4; ++r)
#pragma unroll
      for (int c = 0; c < 4; ++c) acc[r][c] += xv[r] * wv[c];
  }

  f32x4 bv = *reinterpret_cast<const f32x4*>(&bias[tc * 4]);
#pragma unroll
  for (int r = 0; r < 4; ++r)
#pragma unroll
    for (int c = 0; c < 4; ++c) acc[r][c] += bv[c];

  float inv[4];
#pragma unroll
  for (int r = 0; r < 4; ++r) {
    float s = acc[r][0] * acc[r][0] + acc[r][1] * acc[r][1] +
              acc[r][2] * acc[r][2] + acc[r][3] * acc[r][3];
#pragma unroll
    for (int d = 1; d < 32; d <<= 1) s += __shfl_xor(s, d, 32);
    inv[r] = 1.f / fmaxf(sqrtf(s), 1e-12f);
  }

#pragma unroll
  for (int r = 0; r < 4; ++r) {
    u16x4 hv;
#pragma unroll
    for (int c = 0; c < 4; ++c) hv[c] = f2bf(acc[r][c] * inv[r]);
    *reinterpret_cast<u16x4*>(&hn[(size_t)(rbase + tr * 4 + r) * ND + tc * 4]) = hv;
  }
#pragma unroll
  for (int c = 0; c < 4; ++c) {
    u16x4 tv;
#pragma unroll
    for (int r = 0; r < 4; ++r) tv[r] = f2bf(acc[r][c]);
    *reinterpret_cast<u16x4*>(
        &hT[((size_t)b * ND + tc * 4 + c) * NN + nb + tr * 4]) = tv;
  }
}

// K2: part[kh] = (edge * (hn hn^T)) @ h  over this block's 512-key range.
// 512 blocks = (b = bid&7 [XCD], qt 128 q-rows, kh key-quarter), 8 waves,
// 2 blocks/CU (LDS exactly 80 KB). Double-buffered K/V staged via
// global_load_lds; m201-style counted vmcnt(8) + raw s_barrier so the next
// tile's 8 loads stay in flight across the barrier (no vmcnt(0) drain).
__global__ __launch_bounds__(512, 4) void k_fused(
    const float* __restrict__ edge,
    const unsigned short* __restrict__ hn,
    const unsigned short* __restrict__ hT,
    float* __restrict__ part) {
  __shared__ __align__(16) unsigned short Klds[2][64 * 128];  // [buf][key][d] swz
  __shared__ __align__(16) unsigned short Vlds[2][128 * 64];  // [buf][feat][key] swz
  __shared__ __align__(16) unsigned short p_lds[8][16][64];   // slot-XOR swizzled

  const int tid = threadIdx.x;
  const int w = tid >> 6;
  const int l = tid & 63;
  const int m = l & 15;
  const int g = l >> 4;

  const int bid = blockIdx.x;
  const int b = bid & 7;          // XCD-batch affinity
  const int qt = (bid >> 3) & 15;
  const int kh = bid >> 7;        // 0..3 key quarter

  const int q0 = qt * 128 + w * 16;
  const unsigned short* hnb = hn + (size_t)b * NN * ND;
  const unsigned short* hTb = hT + (size_t)b * ND * NN;

  // Q fragments (one-time)
  bf16x8 bq[4];
  {
    const unsigned short* qp = hnb + (size_t)(q0 + m) * ND + g * 8;
#pragma unroll
    for (int kst = 0; kst < 4; ++kst)
      bq[kst] = *reinterpret_cast<const bf16x8*>(qp + kst * 32);
  }

  f32x4 acc_o[8];
#pragma unroll
  for (int i = 0; i < 8; ++i) acc_o[i] = (f32x4){0.f, 0.f, 0.f, 0.f};

  const float* ep = edge + (size_t)b * NN * NN + (size_t)(q0 + m) * NN + kh * 512;

  // stage one 64-key tile (4 gl_lds per thread-slot group; inverse-swizzled src)
  auto STAGE = [&](int kt, int buf) {
    const int kb = kh * 512 + kt * 64;
#pragma unroll
    for (int i = 0; i < 2; ++i) {
      int ch = tid + i * 512;
      int r = ch >> 4, c = ch & 15;
      int sc = c ^ (r & 7);
      stage16(hnb + (size_t)(kb + r) * ND + sc * 8,
              (char*)&Klds[buf][0] + (w * 64 + i * 512) * 16);
    }
#pragma unroll
    for (int i = 0; i < 2; ++i) {
      int ch = tid + i * 512;
      int f = ch >> 3, c = ch & 7;
      int sc = c ^ (f & 7);
      stage16(hTb + (size_t)f * NN + kb + sc * 8,
              (char*)&Vlds[buf][0] + (w * 64 + i * 512) * 16);
    }
  };

  // prologue: tile 0 into buf 0 + edge tile 0
  STAGE(0, 0);
  f32x4 eg[4], egn[4];
#pragma unroll
  for (int ct = 0; ct < 4; ++ct)
    eg[ct] = __builtin_nontemporal_load(
        reinterpret_cast<const f32x4*>(ep + ct * 16 + g * 4));

  for (int kt = 0; kt < 8; ++kt) {
    const int A = kt & 1;

    if (kt < 7) {
      STAGE(kt + 1, A ^ 1);  // 4 vmem
      const float* epn = ep + (kt + 1) * 64;
#pragma unroll
      for (int ct = 0; ct < 4; ++ct)  // 4 vmem
        egn[ct] = __builtin_nontemporal_load(
            reinterpret_cast<const f32x4*>(epn + ct * 16 + g * 4));
      // keep the 8 newest (tile kt+1) in flight; everything older (tile kt's
      // staging + edge) has landed.
      asm volatile("s_waitcnt vmcnt(8)" ::: "memory");
    } else {
      asm volatile("s_waitcnt vmcnt(0)" ::: "memory");
    }
    __builtin_amdgcn_s_barrier();  // all waves: tile kt data visible in LDS

    const unsigned short* Ka = &Klds[A][0];
    const unsigned short* Va = &Vlds[A][0];

    // ---- S^T = K Q^T (rows = keys, cols = q)
    f32x4 st[4];
#pragma unroll
    for (int ct = 0; ct < 4; ++ct) {
      st[ct] = (f32x4){0.f, 0.f, 0.f, 0.f};
      const int r = ct * 16 + m;
#pragma unroll
      for (int kst = 0; kst < 4; ++kst) {
        const int slot = (kst * 4 + g) ^ (r & 7);
        bf16x8 ak = *reinterpret_cast<const bf16x8*>(&Ka[r * 128 + slot * 8]);
        st[ct] = __builtin_amdgcn_mfma_f32_16x16x32_bf16(ak, bq[kst], st[ct], 0, 0, 0);
      }
    }

    // ---- gate with edge; pack P[q=m][64 keys] into per-wave LDS (slot-XOR)
#pragma unroll
    for (int ct = 0; ct < 4; ++ct) {
      u16x4 pv;
#pragma unroll
      for (int r = 0; r < 4; ++r) pv[r] = f2bf(eg[ct][r] * st[ct][r]);
      const int ls = ct * 2 + (g >> 1);         // logical 16B slot
      const int ps = ls ^ (m & 7);              // physical slot
      *reinterpret_cast<u16x4*>(&p_lds[w][m][ps * 8 + (g & 1) * 4]) = pv;
    }

    // ---- out += P @ h
#pragma unroll
    for (int kst2 = 0; kst2 < 2; ++kst2) {
      const int psa = (kst2 * 4 + g) ^ (m & 7);
      bf16x8 ap = *reinterpret_cast<const bf16x8*>(&p_lds[w][m][psa * 8]);
#pragma unroll
      for (int ct2 = 0; ct2 < 8; ++ct2) {
        const int c2 = ct2 * 16 + m;
        const int slot = (kst2 * 4 + g) ^ (c2 & 7);
        bf16x8 bv2 = *reinterpret_cast<const bf16x8*>(&Va[c2 * 64 + slot * 8]);
        acc_o[ct2] = __builtin_amdgcn_mfma_f32_16x16x32_bf16(ap, bv2, acc_o[ct2], 0, 0, 0);
      }
    }

#pragma unroll
    for (int ct = 0; ct < 4; ++ct) eg[ct] = egn[ct];

    // protect buffer A: next iteration stages tile kt+2 into it
    __builtin_amdgcn_s_barrier();
  }

  // plain stores of this key-quarter's partial (no atomics)
  float* pb = part + (size_t)kh * (NB * NN * ND) + ((size_t)b * NN + q0) * ND;
#pragma unroll
  for (int ct2 = 0; ct2 < 8; ++ct2)
#pragma unroll
    for (int r = 0; r < 4; ++r)
      pb[(size_t)(g * 4 + r) * ND + ct2 * 16 + m] = acc_o[ct2][r];
}

// merge 4 key-quarter partials + ReLU
__global__ __launch_bounds__(256) void k_merge(const float* __restrict__ part,
                                               float* __restrict__ out, int n4) {
  int i = blockIdx.x * 256 + threadIdx.x;
  if (i >= n4) return;
  const f32x4* p = reinterpret_cast<const f32x4*>(part);
  const size_t s = (size_t)NB * NN * ND / 4;
  f32x4 v = p[i] + p[i + s] + p[i + 2 * s] + p[i + 3 * s];
#pragma unroll
  for (int j = 0; j < 4; ++j) v[j] = fmaxf(v[j], 0.f);
  reinterpret_cast<f32x4*>(out)[i] = v;
}

extern "C" void kernel_launch(void* const* d_in, const int* in_sizes, int n_in,
                              void* d_out, int out_size, void* d_ws, size_t ws_size,
                              hipStream_t stream) {
  const float* x = (const float*)d_in[0];
  const float* edge = (const float*)d_in[1];
  const float* W = (const float*)d_in[2];
  const float* bias = (const float*)d_in[3];
  float* out = (float*)d_out;

  unsigned short* hn = (unsigned short*)d_ws;                  // 4 MB
  unsigned short* hT = hn + (size_t)NB * NN * ND;              // 4 MB
  float* part = (float*)((char*)d_ws + 2 * (size_t)NB * NN * ND * 2);  // 32 MB

  k_linear<<<dim3((NB * NN) / 64), dim3(512), 0, stream>>>(x, W, bias, hn, hT);
  k_fused<<<dim3(512), dim3(512), 0, stream>>>(edge, hn, hT, part);
  const int n4 = out_size / 4;
  k_merge<<<dim3((n4 + 255) / 256), dim3(256), 0, stream>>>(part, out, n4);
}